// Round 2
// baseline (168.476 us; speedup 1.0000x reference)
//
#include <hip/hip_runtime.h>
#include <hip/hip_bf16.h>

// ---------- types ----------
typedef short bf16x8 __attribute__((ext_vector_type(8)));   // 8 bf16 = 4 VGPR (MFMA A/B frag)
typedef float fx4    __attribute__((ext_vector_type(4)));   // MFMA C/D frag
typedef unsigned uint32x2 __attribute__((ext_vector_type(2)));

#if __has_builtin(__builtin_amdgcn_exp2f)
#define EXP2 __builtin_amdgcn_exp2f
#else
#define EXP2 exp2f
#endif

// packed fp32x2 -> bf16x2 (RNE), emits v_cvt_pk_bf16_f32 on gfx950
__device__ __forceinline__ unsigned pk2(float a, float b) {
  union { __hip_bfloat162 h; unsigned u; } cv;
  cv.h = __float22bfloat162_rn(float2{a, b});
  return cv.u;
}
__device__ __forceinline__ uint2 pk4(const fx4& v) {
  uint2 r;
  r.x = pk2(v[0], v[1]);
  r.y = pk2(v[2], v[3]);
  return r;
}

// async global->LDS, 16B per lane. LDS dest = wave-uniform base + lane*16.
__device__ __forceinline__ void gld16(const void* g, void* l) {
  __builtin_amdgcn_global_load_lds(
      (const __attribute__((address_space(1))) unsigned int*)g,
      (__attribute__((address_space(3))) unsigned int*)l, 16, 0, 0);
}

// ---- barriers that do NOT drain vmcnt (keep register prefetches in flight) ----
__device__ __forceinline__ void bar_raw() {
  asm volatile("s_barrier" ::: "memory");
}
__device__ __forceinline__ void bar_lgkm() {
  asm volatile("s_waitcnt lgkmcnt(0)\ns_barrier" ::: "memory");
}
__device__ __forceinline__ void bar_lgkm_vm4() {
  asm volatile("s_waitcnt vmcnt(4) lgkmcnt(0)\ns_barrier" ::: "memory");
}
// full drain barrier (for gld16 double-buffer handoff in attn)
__device__ __forceinline__ void bar_vm_lgkm() {
  asm volatile("s_waitcnt vmcnt(0) lgkmcnt(0)\ns_barrier" ::: "memory");
}
__device__ __forceinline__ void cfence() { asm volatile("" ::: "memory"); }

// ---------- prep: x cast + both weight transposes, one launch ----------
__global__ __launch_bounds__(256) void prep_kernel(
    const float* __restrict__ x, const float* __restrict__ Wq,
    const float* __restrict__ Wkv, const float* __restrict__ Wo,
    short* __restrict__ xb, short* __restrict__ WallT, short* __restrict__ WoT,
    float qscale) {
  const int bx = blockIdx.x, tid = threadIdx.x;
  if (bx < 4096) {
    int i = bx * 256 + tid;
    const float4 s = *(const float4*)(x + (size_t)i * 4);
    uint2 o; o.x = pk2(s.x, s.y); o.y = pk2(s.z, s.w);
    *(uint2*)(xb + (size_t)i * 4) = o;
    return;
  }
  __shared__ float t[32][33];
  const int idx = bx - 4096;            // 0..1023
  const int wb = idx & 63, kt = (idx >> 6) * 32;
  const bool mode0 = wb < 48;
  const int ct = (mode0 ? wb : wb - 48) * 32;
  const int tx = tid & 31, ty = tid >> 5;
  short* outT = mode0 ? WallT : WoT;
#pragma unroll
  for (int s = 0; s < 4; ++s) {
    int k = kt + ty + s * 8;
    int c = ct + tx;
    float v;
    if (mode0) v = (c < 512) ? Wq[(size_t)k * 512 + c] * qscale
                             : Wkv[(size_t)k * 1024 + (c - 512)];
    else       v = Wo[(size_t)k * 512 + c];
    t[ty + s * 8][tx] = v;
  }
  __syncthreads();
#pragma unroll
  for (int s = 0; s < 4; ++s) {
    int c = ct + ty + s * 8;
    int k = kt + tx;
    unsigned u = __float_as_uint(t[tx][ty + s * 8]);
    u = (u + 0x7fffu + ((u >> 16) & 1u)) >> 16;
    outT[(size_t)c * 512 + k] = (short)u;
  }
}

// ---------- QKV GEMM: 128x128 tile, BK=64, A reg-prefetch + B gld16/vmcnt(4) ----------
__global__ __launch_bounds__(256) void gemm_qkv(
    const short* __restrict__ A, const short* __restrict__ Bt,
    short* __restrict__ oq, short* __restrict__ ok, short* __restrict__ ovT) {
  __shared__ short As[2 * 128 * 32];   // [slab][row][32k]
  __shared__ short Bs[2 * 128 * 32];
  const int K = 512;
  const int tid = threadIdx.x;
  const int wave = tid >> 6, lane = tid & 63;
  const int quad = lane >> 4, l15 = lane & 15;
  const int wm = wave >> 1, wn = wave & 1;
  const int m0 = blockIdx.y * 128, n0 = blockIdx.x * 128;
  const bool swapped = (n0 < 1024);

  int arow[4], aoff[4];
#pragma unroll
  for (int c = 0; c < 4; ++c) {
    int u = c * 256 + tid;
    int slab = u >> 9, r2 = u & 511;
    arow[c] = r2 >> 2;
    aoff[c] = slab * 32 + (r2 & 3) * 8;
  }

  fx4 acc[4][4];
#pragma unroll
  for (int i = 0; i < 4; ++i)
#pragma unroll
    for (int j = 0; j < 4; ++j) acc[i][j] = fx4{0.f, 0.f, 0.f, 0.f};

  bf16x8 apre[4];
#pragma unroll
  for (int c = 0; c < 4; ++c)
    apre[c] = *(const bf16x8*)(A + (size_t)(m0 + arow[c]) * K + aoff[c]);

  for (int k0 = 0; k0 < K; k0 += 64) {
    bar_raw();
#pragma unroll
    for (int c = 0; c < 4; ++c)
      *(bf16x8*)(As + (size_t)(c * 256 + tid) * 8) = apre[c];
#pragma unroll
    for (int c = 0; c < 4; ++c) {
      int u = c * 256 + tid;
      int slab = u >> 9, r2 = u & 511;
      gld16(Bt + (size_t)(n0 + (r2 >> 2)) * K + k0 + slab * 32 + (r2 & 3) * 8,
            Bs + (size_t)(c * 256 + wave * 64) * 8);
    }
    cfence();
    {
      int kn = (k0 + 64) & 511;
#pragma unroll
      for (int c = 0; c < 4; ++c)
        apre[c] = *(const bf16x8*)(A + (size_t)(m0 + arow[c]) * K + kn + aoff[c]);
    }
    bar_lgkm_vm4();

#pragma unroll
    for (int ks2 = 0; ks2 < 2; ++ks2) {
      bf16x8 af[4], bfr[4];
#pragma unroll
      for (int i = 0; i < 4; ++i)
        af[i] = *(const bf16x8*)(As + ks2 * 4096 + (wm * 64 + i * 16 + l15) * 32 + quad * 8);
#pragma unroll
      for (int i = 0; i < 4; ++i)
        bfr[i] = *(const bf16x8*)(Bs + ks2 * 4096 + (wn * 64 + i * 16 + l15) * 32 + quad * 8);
      if (swapped) {
#pragma unroll
        for (int mi = 0; mi < 4; ++mi)
#pragma unroll
          for (int ni = 0; ni < 4; ++ni)
            acc[mi][ni] = __builtin_amdgcn_mfma_f32_16x16x32_bf16(bfr[ni], af[mi], acc[mi][ni], 0, 0, 0);
      } else {
#pragma unroll
        for (int mi = 0; mi < 4; ++mi)
#pragma unroll
          for (int ni = 0; ni < 4; ++ni)
            acc[mi][ni] = __builtin_amdgcn_mfma_f32_16x16x32_bf16(af[mi], bfr[ni], acc[mi][ni], 0, 0, 0);
      }
    }
  }

  const int rowb = m0 + wm * 64;
  const int colb = n0 + wn * 64;
  const int cls = n0 >> 9;  // 0=q, 1=k, 2=v
  if (cls < 2) {
    short* base = (cls == 0) ? oq : ok;
#pragma unroll
    for (int mi = 0; mi < 4; ++mi) {
      int t = rowb + mi * 16 + l15;
      int bb = t >> 11, ii = t & 2047;
#pragma unroll
      for (int ni = 0; ni < 4; ++ni) {
        int f = (colb + ni * 16 + quad * 4) & 511;
        int hh = f >> 6, dd = f & 63;
        *(uint2*)(base + ((size_t)(bb * 8 + hh) * 2048 + ii) * 64 + dd) = pk4(acc[mi][ni]);
      }
    }
  } else {
#pragma unroll
    for (int mi = 0; mi < 4; ++mi) {
      int rbase = rowb + mi * 16 + quad * 4;
      int bb = rbase >> 11;
      int ii = rbase & 2047;
#pragma unroll
      for (int ni = 0; ni < 4; ++ni) {
        int c = (colb + ni * 16 + l15) & 511;
        int hh = c >> 6, dd = c & 63;
        *(uint2*)(ovT + ((size_t)(bb * 8 + hh) * 64 + dd) * 2048 + ii) = pk4(acc[mi][ni]);
      }
    }
  }
}

// ---------- out-proj GEMM: 64x128 tile, BK=64, full reg-prefetch, fp32+bias ----------
__global__ __launch_bounds__(256) void gemm_out(
    const short* __restrict__ A, const short* __restrict__ Bt,
    float* __restrict__ of, const float* __restrict__ bias) {
  __shared__ short As[2 * 64 * 32];    // 8KB
  __shared__ short Bs[2 * 128 * 32];   // 16KB
  const int K = 512, N = 512;
  const int tid = threadIdx.x;
  const int wave = tid >> 6, lane = tid & 63;
  const int quad = lane >> 4, l15 = lane & 15;
  const int wm = wave >> 1, wn = wave & 1;
  const int m0 = blockIdx.y * 64, n0 = blockIdx.x * 128;

  int arow[2], aoff[2], brow[4], boff[4];
#pragma unroll
  for (int c = 0; c < 2; ++c) {
    int u = c * 256 + tid;
    int slab = u >> 8, r2 = u & 255;
    arow[c] = r2 >> 2; aoff[c] = slab * 32 + (r2 & 3) * 8;
  }
#pragma unroll
  for (int c = 0; c < 4; ++c) {
    int u = c * 256 + tid;
    int slab = u >> 9, r2 = u & 511;
    brow[c] = r2 >> 2; boff[c] = slab * 32 + (r2 & 3) * 8;
  }

  fx4 acc[2][4];
#pragma unroll
  for (int i = 0; i < 2; ++i)
#pragma unroll
    for (int j = 0; j < 4; ++j) acc[i][j] = fx4{0.f, 0.f, 0.f, 0.f};

  bf16x8 apre[2], bpre[4];
#pragma unroll
  for (int c = 0; c < 2; ++c)
    apre[c] = *(const bf16x8*)(A + (size_t)(m0 + arow[c]) * K + aoff[c]);
#pragma unroll
  for (int c = 0; c < 4; ++c)
    bpre[c] = *(const bf16x8*)(Bt + (size_t)(n0 + brow[c]) * K + boff[c]);

  for (int k0 = 0; k0 < K; k0 += 64) {
    bar_raw();
#pragma unroll
    for (int c = 0; c < 2; ++c)
      *(bf16x8*)(As + (size_t)(c * 256 + tid) * 8) = apre[c];
#pragma unroll
    for (int c = 0; c < 4; ++c)
      *(bf16x8*)(Bs + (size_t)(c * 256 + tid) * 8) = bpre[c];
    {
      int kn = (k0 + 64) & 511;
#pragma unroll
      for (int c = 0; c < 2; ++c)
        apre[c] = *(const bf16x8*)(A + (size_t)(m0 + arow[c]) * K + kn + aoff[c]);
#pragma unroll
      for (int c = 0; c < 4; ++c)
        bpre[c] = *(const bf16x8*)(Bt + (size_t)(n0 + brow[c]) * K + kn + boff[c]);
    }
    bar_lgkm();

#pragma unroll
    for (int ks2 = 0; ks2 < 2; ++ks2) {
      bf16x8 af[2], bfr[4];
#pragma unroll
      for (int i = 0; i < 2; ++i)
        af[i] = *(const bf16x8*)(As + ks2 * 2048 + (wm * 32 + i * 16 + l15) * 32 + quad * 8);
#pragma unroll
      for (int i = 0; i < 4; ++i)
        bfr[i] = *(const bf16x8*)(Bs + ks2 * 4096 + (wn * 64 + i * 16 + l15) * 32 + quad * 8);
#pragma unroll
      for (int mi = 0; mi < 2; ++mi)
#pragma unroll
        for (int ni = 0; ni < 4; ++ni)
          acc[mi][ni] = __builtin_amdgcn_mfma_f32_16x16x32_bf16(af[mi], bfr[ni], acc[mi][ni], 0, 0, 0);
    }
  }

  const int rowb = m0 + wm * 32;
  const int colb = n0 + wn * 64;
#pragma unroll
  for (int mi = 0; mi < 2; ++mi)
#pragma unroll
    for (int ni = 0; ni < 4; ++ni) {
      int cg = colb + ni * 16 + l15;
      float bv = bias[cg];
#pragma unroll
      for (int r = 0; r < 4; ++r) {
        int rg = rowb + mi * 16 + quad * 4 + r;
        of[(size_t)rg * N + cg] = acc[mi][ni][r] + bv;
      }
    }
}

// ---------- flash attention v3: 16 q-rows/wave, BJ=64, 4 blocks/CU ----------
// Q,K: [bh=32][2048][64] bf16 ; Vt: [bh][64][2048] bf16 ; O: [b][2048][512] bf16
// v3 change vs v2: v2 proved attn is LATENCY-bound (deleting all P-LDS traffic
// + 3.1M bank conflicts changed dur by 0%): at grid=512 we had 2 waves/SIMD
// and nothing to hide the ds_read->MFMA->exp2->butterfly->MFMA chain.
// Fix: halve rows/wave (32->16), double grid to (32,32)=1024 blocks
// -> 4 blocks/CU (LDS 32KB caps at 5), 16 waves/CU, 4 waves/SIMD.
// LDS read traffic doubles (16 b128/wave-iter now feed 18 MFMA not 36) but
// the LDS ceiling (~27us total) stays below target; latency hiding doubles.
// P stays fully in-register (quad butterfly via permlane32/16_swap);
// K/V staged by gld16 DMA, double-buffered, one full-drain barrier/iter.
__global__ __launch_bounds__(256) void attn_kernel(
    const short* __restrict__ Q, const short* __restrict__ K,
    const short* __restrict__ Vt, short* __restrict__ O) {
  __shared__ short Ks[2 * 64 * 64];    // [buf][j][d], seg-swizzled (seg ^ row&7)
  __shared__ short Vs[2 * 64 * 64];    // [buf][d][j], seg-swizzled

  const int tid = threadIdx.x;
  const int wave = tid >> 6, lane = tid & 63;
  const int quad = lane >> 4, l15 = lane & 15;
  const int bh = blockIdx.y;
  const int b = bh >> 3, h = bh & 7;
  const int i0 = blockIdx.x * 64 + wave * 16;

  const int idx0 = tid, idx1 = 256 + tid;
  const int row0 = idx0 >> 3, sg0 = (idx0 & 7) ^ (row0 & 7);
  const int row1 = idx1 >> 3, sg1 = (idx1 & 7) ^ (row1 & 7);
  const short* Kb = K + (size_t)bh * 2048 * 64;
  const short* Vb = Vt + (size_t)bh * 64 * 2048;

  // Q as B-operand fragments: [ks]; i = l15, d = ks*32+quad*8+e
  bf16x8 qf[2];
#pragma unroll
  for (int ks = 0; ks < 2; ++ks)
    qf[ks] = *(const bf16x8*)(Q + ((size_t)bh * 2048 + i0 + l15) * 64 + ks * 32 + quad * 8);

  bf16x8 ones;
#pragma unroll
  for (int c = 0; c < 8; ++c) ones[c] = (short)0x3F80;

  fx4 oacc[4];                         // [dt], O^T: row d=quad*4+r, col i=l15
  fx4 acc_l = fx4{0.f, 0.f, 0.f, 0.f};
#pragma unroll
  for (int dt = 0; dt < 4; ++dt) oacc[dt] = fx4{0.f, 0.f, 0.f, 0.f};

  // prologue: DMA tile 0 -> buf 0 (LDS dest linear: base + lane*16)
  gld16(Kb + (size_t)row0 * 64 + sg0 * 8, Ks + wave * 512);
  gld16(Kb + (size_t)row1 * 64 + sg1 * 8, Ks + 2048 + wave * 512);
  gld16(Vb + (size_t)row0 * 2048 + sg0 * 8, Vs + wave * 512);
  gld16(Vb + (size_t)row1 * 2048 + sg1 * 8, Vs + 2048 + wave * 512);

  for (int j0 = 0; j0 < 2048; j0 += 64) {
    const int cur = (j0 >> 6) & 1;
    bar_vm_lgkm();   // buf[cur] DMA complete; every wave's prior LDS reads drained
    if (j0 + 64 < 2048) {              // stage next tile into buf[cur^1]
      const int jn = j0 + 64;
      const int nb = (cur ^ 1) * 4096;
      gld16(Kb + (size_t)(jn + row0) * 64 + sg0 * 8, Ks + nb + wave * 512);
      gld16(Kb + (size_t)(jn + row1) * 64 + sg1 * 8, Ks + nb + 2048 + wave * 512);
      gld16(Vb + (size_t)row0 * 2048 + jn + sg0 * 8, Vs + nb + wave * 512);
      gld16(Vb + (size_t)row1 * 2048 + jn + sg1 * 8, Vs + nb + 2048 + wave * 512);
    }
    const short* Kc = Ks + cur * 4096;
    const short* Vc = Vs + cur * 4096;

    // ---- S^T = K · Q^T ----
    fx4 s[4];
#pragma unroll
    for (int jt = 0; jt < 4; ++jt) s[jt] = fx4{0.f, 0.f, 0.f, 0.f};
#pragma unroll
    for (int ks = 0; ks < 2; ++ks) {
#pragma unroll
      for (int jt = 0; jt < 4; ++jt) {
        bf16x8 kf = *(const bf16x8*)(Kc + (jt * 16 + l15) * 64 + (((ks * 4 + quad) ^ (l15 & 7)) * 8));
        s[jt] = __builtin_amdgcn_mfma_f32_16x16x32_bf16(kf, qf[ks], s[jt], 0, 0, 0);
      }
    }

    // ---- p = exp2(s); in-register quad-butterfly to PV B-operand layout ----
    // lane(q,l15) holds P[i=l15][j=16jt+4q+2h+{0,1}]; PV needs
    // P[i][j=32kj+8q'+2m+{0,1}]: lane(b3,b2)/word(b5,b4,b1) ->
    // lane(b4,b3)/word(b5,b2,b1) = permlane32_swap then permlane16_swap.
    bf16x8 pfr[2];                     // [kj]
    {
      unsigned W[4][2];                // [jt][h]: bf16x2 of j = 16jt+4q+2h,+1
#pragma unroll
      for (int jt = 0; jt < 4; ++jt) {
#pragma unroll
        for (int r = 0; r < 4; ++r) s[jt][r] = EXP2(s[jt][r]);
        W[jt][0] = pk2(s[jt][0], s[jt][1]);
        W[jt][1] = pk2(s[jt][2], s[jt][3]);
      }
#pragma unroll
      for (int k = 0; k < 2; ++k) {    // k = kj = b5
        union { unsigned u[4]; bf16x8 v; } pw;
#pragma unroll
        for (int hh = 0; hh < 2; ++hh) {  // hh = b1
          uint32x2 a = __builtin_amdgcn_permlane32_swap(W[2 * k][hh], W[2 * k + 1][hh], false, false);
          uint32x2 t = __builtin_amdgcn_permlane16_swap(a[0], a[1], false, false);
          pw.u[hh] = t[0];             // b2=0 -> word m=hh
          pw.u[2 + hh] = t[1];         // b2=1 -> word m=2+hh
        }
        pfr[k] = pw.v;
      }
    }

    // ---- O^T += V^T · P^T ; l += 1 · P^T (all operands in registers) ----
#pragma unroll
    for (int kj = 0; kj < 2; ++kj) {
      acc_l = __builtin_amdgcn_mfma_f32_16x16x32_bf16(ones, pfr[kj], acc_l, 0, 0, 0);
#pragma unroll
      for (int dt = 0; dt < 4; ++dt) {
        bf16x8 vf = *(const bf16x8*)(Vc + (dt * 16 + l15) * 64 + (((kj * 4 + quad) ^ (l15 & 7)) * 8));
        oacc[dt] = __builtin_amdgcn_mfma_f32_16x16x32_bf16(vf, pfr[kj], oacc[dt], 0, 0, 0);
      }
    }
  }

  // ---- normalize + write O bf16 [b][n=i][h*64+d]; 4 consecutive d -> b64 ----
  {
    float inv = __builtin_amdgcn_rcpf(acc_l[0]);
    size_t rowbase = ((size_t)b * 2048 + i0 + l15) * 512 + h * 64;
#pragma unroll
    for (int dt = 0; dt < 4; ++dt) {
      fx4 o = oacc[dt] * inv;
      *(uint2*)(O + rowbase + dt * 16 + quad * 4) = pk4(o);
    }
  }
}

// ---------- launch ----------
extern "C" void kernel_launch(void* const* d_in, const int* in_sizes, int n_in,
                              void* d_out, int out_size, void* d_ws, size_t ws_size,
                              hipStream_t stream) {
  const float* x   = (const float*)d_in[0];
  const float* Wq  = (const float*)d_in[1];
  const float* Wkv = (const float*)d_in[2];
  const float* Wo  = (const float*)d_in[3];
  const float* bo  = (const float*)d_in[4];
  float* out = (float*)d_out;

  char* p = (char*)d_ws;
  short* xb    = (short*)p; p += (size_t)8192 * 512 * 2;   // x bf16 [8192,512]
  short* WallT = (short*)p; p += (size_t)1536 * 512 * 2;   // [Wq|Wkv]^T bf16 [1536,512]
  short* WoT   = (short*)p; p += (size_t)512 * 512 * 2;    // Wo^T bf16 [512,512]
  short* qb    = (short*)p; p += (size_t)32 * 2048 * 64 * 2;  // [bh,n,d]
  short* kb    = (short*)p; p += (size_t)32 * 2048 * 64 * 2;  // [bh,n,d]
  short* vTb   = (short*)p; p += (size_t)32 * 64 * 2048 * 2;  // [bh,d,n]
  short* Ob    = (short*)p; p += (size_t)8192 * 512 * 2;   // attn out bf16 [8192,512]

  const float qscale = 0.125f * 1.4426950408889634f;  // d^-0.5 * log2(e)

  prep_kernel<<<5120, 256, 0, stream>>>(x, Wq, Wkv, Wo, xb, WallT, WoT, qscale);
  gemm_qkv<<<dim3(12, 64), 256, 0, stream>>>(xb, WallT, qb, kb, vTb);
  attn_kernel<<<dim3(32, 32), 256, 0, stream>>>(qb, kb, vTb, Ob);
  gemm_out<<<dim3(4, 128), 256, 0, stream>>>(Ob, WoT, out, bo);
}

// Round 3
// 165.786 us; speedup vs baseline: 1.0162x; 1.0162x over previous
//
#include <hip/hip_runtime.h>
#include <hip/hip_bf16.h>

// ---------- types ----------
typedef short bf16x8 __attribute__((ext_vector_type(8)));   // 8 bf16 = 4 VGPR (MFMA A/B frag)
typedef float fx4    __attribute__((ext_vector_type(4)));   // MFMA C/D frag
typedef unsigned uint32x2 __attribute__((ext_vector_type(2)));

#if __has_builtin(__builtin_amdgcn_exp2f)
#define EXP2 __builtin_amdgcn_exp2f
#else
#define EXP2 exp2f
#endif

// packed fp32x2 -> bf16x2 (RNE), emits v_cvt_pk_bf16_f32 on gfx950
__device__ __forceinline__ unsigned pk2(float a, float b) {
  union { __hip_bfloat162 h; unsigned u; } cv;
  cv.h = __float22bfloat162_rn(float2{a, b});
  return cv.u;
}
__device__ __forceinline__ uint2 pk4(const fx4& v) {
  uint2 r;
  r.x = pk2(v[0], v[1]);
  r.y = pk2(v[2], v[3]);
  return r;
}

// async global->LDS, 16B per lane. LDS dest = wave-uniform base + lane*16.
__device__ __forceinline__ void gld16(const void* g, void* l) {
  __builtin_amdgcn_global_load_lds(
      (const __attribute__((address_space(1))) unsigned int*)g,
      (__attribute__((address_space(3))) unsigned int*)l, 16, 0, 0);
}

// ---- barriers that do NOT drain vmcnt (keep register prefetches in flight) ----
__device__ __forceinline__ void bar_raw() {
  asm volatile("s_barrier" ::: "memory");
}
__device__ __forceinline__ void bar_lgkm() {
  asm volatile("s_waitcnt lgkmcnt(0)\ns_barrier" ::: "memory");
}
__device__ __forceinline__ void bar_lgkm_vm4() {
  asm volatile("s_waitcnt vmcnt(4) lgkmcnt(0)\ns_barrier" ::: "memory");
}
// full drain barrier (for gld16 double-buffer handoff in attn)
__device__ __forceinline__ void bar_vm_lgkm() {
  asm volatile("s_waitcnt vmcnt(0) lgkmcnt(0)\ns_barrier" ::: "memory");
}
__device__ __forceinline__ void cfence() { asm volatile("" ::: "memory"); }

// ---------- prep: x cast + both weight transposes, one launch ----------
__global__ __launch_bounds__(256) void prep_kernel(
    const float* __restrict__ x, const float* __restrict__ Wq,
    const float* __restrict__ Wkv, const float* __restrict__ Wo,
    short* __restrict__ xb, short* __restrict__ WallT, short* __restrict__ WoT,
    float qscale) {
  const int bx = blockIdx.x, tid = threadIdx.x;
  if (bx < 4096) {
    int i = bx * 256 + tid;
    const float4 s = *(const float4*)(x + (size_t)i * 4);
    uint2 o; o.x = pk2(s.x, s.y); o.y = pk2(s.z, s.w);
    *(uint2*)(xb + (size_t)i * 4) = o;
    return;
  }
  __shared__ float t[32][33];
  const int idx = bx - 4096;            // 0..1023
  const int wb = idx & 63, kt = (idx >> 6) * 32;
  const bool mode0 = wb < 48;
  const int ct = (mode0 ? wb : wb - 48) * 32;
  const int tx = tid & 31, ty = tid >> 5;
  short* outT = mode0 ? WallT : WoT;
#pragma unroll
  for (int s = 0; s < 4; ++s) {
    int k = kt + ty + s * 8;
    int c = ct + tx;
    float v;
    if (mode0) v = (c < 512) ? Wq[(size_t)k * 512 + c] * qscale
                             : Wkv[(size_t)k * 1024 + (c - 512)];
    else       v = Wo[(size_t)k * 512 + c];
    t[ty + s * 8][tx] = v;
  }
  __syncthreads();
#pragma unroll
  for (int s = 0; s < 4; ++s) {
    int c = ct + ty + s * 8;
    int k = kt + tx;
    unsigned u = __float_as_uint(t[tx][ty + s * 8]);
    u = (u + 0x7fffu + ((u >> 16) & 1u)) >> 16;
    outT[(size_t)c * 512 + k] = (short)u;
  }
}

// ---------- QKV GEMM: 128x128 tile, BK=64, A reg-prefetch + B gld16/vmcnt(4) ----------
// XCD-residency swizzle: 768 blocks flat; xcd = blk&7 (HW round-robin), each
// XCD gets 8 m-panels (1MB A) + the whole 1.5MB B panel -> <4MB L2, L2-resident.
__global__ __launch_bounds__(256) void gemm_qkv(
    const short* __restrict__ A, const short* __restrict__ Bt,
    short* __restrict__ oq, short* __restrict__ ok, short* __restrict__ ovT) {
  __shared__ short As[2 * 128 * 32];   // [slab][row][32k]
  __shared__ short Bs[2 * 128 * 32];
  const int K = 512;
  const int tid = threadIdx.x;
  const int wave = tid >> 6, lane = tid & 63;
  const int quad = lane >> 4, l15 = lane & 15;
  const int wm = wave >> 1, wn = wave & 1;
  const int blk = blockIdx.x;          // 0..767
  const int xcd = blk & 7, slot = blk >> 3;      // slot 0..95
  const int m0 = ((slot / 12) * 8 + xcd) * 128;  // m-tile 0..63
  const int n0 = (slot % 12) * 128;              // n-tile 0..11
  const bool swapped = (n0 < 1024);

  int arow[4], aoff[4];
#pragma unroll
  for (int c = 0; c < 4; ++c) {
    int u = c * 256 + tid;
    int slab = u >> 9, r2 = u & 511;
    arow[c] = r2 >> 2;
    aoff[c] = slab * 32 + (r2 & 3) * 8;
  }

  fx4 acc[4][4];
#pragma unroll
  for (int i = 0; i < 4; ++i)
#pragma unroll
    for (int j = 0; j < 4; ++j) acc[i][j] = fx4{0.f, 0.f, 0.f, 0.f};

  bf16x8 apre[4];
#pragma unroll
  for (int c = 0; c < 4; ++c)
    apre[c] = *(const bf16x8*)(A + (size_t)(m0 + arow[c]) * K + aoff[c]);

  for (int k0 = 0; k0 < K; k0 += 64) {
    bar_raw();
#pragma unroll
    for (int c = 0; c < 4; ++c)
      *(bf16x8*)(As + (size_t)(c * 256 + tid) * 8) = apre[c];
#pragma unroll
    for (int c = 0; c < 4; ++c) {
      int u = c * 256 + tid;
      int slab = u >> 9, r2 = u & 511;
      gld16(Bt + (size_t)(n0 + (r2 >> 2)) * K + k0 + slab * 32 + (r2 & 3) * 8,
            Bs + (size_t)(c * 256 + wave * 64) * 8);
    }
    cfence();
    {
      int kn = (k0 + 64) & 511;
#pragma unroll
      for (int c = 0; c < 4; ++c)
        apre[c] = *(const bf16x8*)(A + (size_t)(m0 + arow[c]) * K + kn + aoff[c]);
    }
    bar_lgkm_vm4();

#pragma unroll
    for (int ks2 = 0; ks2 < 2; ++ks2) {
      bf16x8 af[4], bfr[4];
#pragma unroll
      for (int i = 0; i < 4; ++i)
        af[i] = *(const bf16x8*)(As + ks2 * 4096 + (wm * 64 + i * 16 + l15) * 32 + quad * 8);
#pragma unroll
      for (int i = 0; i < 4; ++i)
        bfr[i] = *(const bf16x8*)(Bs + ks2 * 4096 + (wn * 64 + i * 16 + l15) * 32 + quad * 8);
      if (swapped) {
#pragma unroll
        for (int mi = 0; mi < 4; ++mi)
#pragma unroll
          for (int ni = 0; ni < 4; ++ni)
            acc[mi][ni] = __builtin_amdgcn_mfma_f32_16x16x32_bf16(bfr[ni], af[mi], acc[mi][ni], 0, 0, 0);
      } else {
#pragma unroll
        for (int mi = 0; mi < 4; ++mi)
#pragma unroll
          for (int ni = 0; ni < 4; ++ni)
            acc[mi][ni] = __builtin_amdgcn_mfma_f32_16x16x32_bf16(af[mi], bfr[ni], acc[mi][ni], 0, 0, 0);
      }
    }
  }

  const int rowb = m0 + wm * 64;
  const int colb = n0 + wn * 64;
  const int cls = n0 >> 9;  // 0=q, 1=k, 2=v
  if (cls < 2) {
    short* base = (cls == 0) ? oq : ok;
#pragma unroll
    for (int mi = 0; mi < 4; ++mi) {
      int t = rowb + mi * 16 + l15;
      int bb = t >> 11, ii = t & 2047;
#pragma unroll
      for (int ni = 0; ni < 4; ++ni) {
        int f = (colb + ni * 16 + quad * 4) & 511;
        int hh = f >> 6, dd = f & 63;
        *(uint2*)(base + ((size_t)(bb * 8 + hh) * 2048 + ii) * 64 + dd) = pk4(acc[mi][ni]);
      }
    }
  } else {
#pragma unroll
    for (int mi = 0; mi < 4; ++mi) {
      int rbase = rowb + mi * 16 + quad * 4;
      int bb = rbase >> 11;
      int ii = rbase & 2047;
#pragma unroll
      for (int ni = 0; ni < 4; ++ni) {
        int c = (colb + ni * 16 + l15) & 511;
        int hh = c >> 6, dd = c & 63;
        *(uint2*)(ovT + ((size_t)(bb * 8 + hh) * 64 + dd) * 2048 + ii) = pk4(acc[mi][ni]);
      }
    }
  }
}

// ---------- out-proj GEMM: 64x128 tile, BK=64, full reg-prefetch, fp32+bias ----------
__global__ __launch_bounds__(256) void gemm_out(
    const short* __restrict__ A, const short* __restrict__ Bt,
    float* __restrict__ of, const float* __restrict__ bias) {
  __shared__ short As[2 * 64 * 32];    // 8KB
  __shared__ short Bs[2 * 128 * 32];   // 16KB
  const int K = 512, N = 512;
  const int tid = threadIdx.x;
  const int wave = tid >> 6, lane = tid & 63;
  const int quad = lane >> 4, l15 = lane & 15;
  const int wm = wave >> 1, wn = wave & 1;
  const int m0 = blockIdx.y * 64, n0 = blockIdx.x * 128;

  int arow[2], aoff[2], brow[4], boff[4];
#pragma unroll
  for (int c = 0; c < 2; ++c) {
    int u = c * 256 + tid;
    int slab = u >> 8, r2 = u & 255;
    arow[c] = r2 >> 2; aoff[c] = slab * 32 + (r2 & 3) * 8;
  }
#pragma unroll
  for (int c = 0; c < 4; ++c) {
    int u = c * 256 + tid;
    int slab = u >> 9, r2 = u & 511;
    brow[c] = r2 >> 2; boff[c] = slab * 32 + (r2 & 3) * 8;
  }

  fx4 acc[2][4];
#pragma unroll
  for (int i = 0; i < 2; ++i)
#pragma unroll
    for (int j = 0; j < 4; ++j) acc[i][j] = fx4{0.f, 0.f, 0.f, 0.f};

  bf16x8 apre[2], bpre[4];
#pragma unroll
  for (int c = 0; c < 2; ++c)
    apre[c] = *(const bf16x8*)(A + (size_t)(m0 + arow[c]) * K + aoff[c]);
#pragma unroll
  for (int c = 0; c < 4; ++c)
    bpre[c] = *(const bf16x8*)(Bt + (size_t)(n0 + brow[c]) * K + boff[c]);

  for (int k0 = 0; k0 < K; k0 += 64) {
    bar_raw();
#pragma unroll
    for (int c = 0; c < 2; ++c)
      *(bf16x8*)(As + (size_t)(c * 256 + tid) * 8) = apre[c];
#pragma unroll
    for (int c = 0; c < 4; ++c)
      *(bf16x8*)(Bs + (size_t)(c * 256 + tid) * 8) = bpre[c];
    {
      int kn = (k0 + 64) & 511;
#pragma unroll
      for (int c = 0; c < 2; ++c)
        apre[c] = *(const bf16x8*)(A + (size_t)(m0 + arow[c]) * K + kn + aoff[c]);
#pragma unroll
      for (int c = 0; c < 4; ++c)
        bpre[c] = *(const bf16x8*)(Bt + (size_t)(n0 + brow[c]) * K + kn + boff[c]);
    }
    bar_lgkm();

#pragma unroll
    for (int ks2 = 0; ks2 < 2; ++ks2) {
      bf16x8 af[2], bfr[4];
#pragma unroll
      for (int i = 0; i < 2; ++i)
        af[i] = *(const bf16x8*)(As + ks2 * 2048 + (wm * 32 + i * 16 + l15) * 32 + quad * 8);
#pragma unroll
      for (int i = 0; i < 4; ++i)
        bfr[i] = *(const bf16x8*)(Bs + ks2 * 4096 + (wn * 64 + i * 16 + l15) * 32 + quad * 8);
#pragma unroll
      for (int mi = 0; mi < 2; ++mi)
#pragma unroll
        for (int ni = 0; ni < 4; ++ni)
          acc[mi][ni] = __builtin_amdgcn_mfma_f32_16x16x32_bf16(af[mi], bfr[ni], acc[mi][ni], 0, 0, 0);
    }
  }

  const int rowb = m0 + wm * 32;
  const int colb = n0 + wn * 64;
#pragma unroll
  for (int mi = 0; mi < 2; ++mi)
#pragma unroll
    for (int ni = 0; ni < 4; ++ni) {
      int cg = colb + ni * 16 + l15;
      float bv = bias[cg];
#pragma unroll
      for (int r = 0; r < 4; ++r) {
        int rg = rowb + mi * 16 + quad * 4 + r;
        of[(size_t)rg * N + cg] = acc[mi][ni][r] + bv;
      }
    }
}

// ---------- flash attention v4: 32 q-rows/wave, BJ=64, XCD-residency swizzle ----------
// Q,K: [bh=32][2048][64] bf16 ; Vt: [bh][64][2048] bf16 ; O: [b][2048][512] bf16
// v4 = v2 geometry (32 rows/wave; LDS read traffic half of v3's; occupancy
// proven irrelevant by v3's null) + two changes:
//  (a) XCD-residency swizzle: flat grid 512; xcd = blk&7 (HW round-robin
//      dispatch), bh = (slot>>4)*8 + xcd -> each bh's 16 q-blocks live on ONE
//      XCD. Per-XCD concurrent K/V footprint = 4 bh x 512KB = 2MB < 4MB L2
//      (was ~16MB: every XCD touched all 32 bh -> L2 thrash, all tile DMA
//      served at L3/HBM latency ~450-900cy; FETCH 69.7MB = 2.9x unique).
//      With residency, K/V comes from HBM once (16MB) and re-reads are L2
//      hits (~200cy) fully covered by the iteration.
//  (b) T5 s_setprio(1) around the MFMA clusters (attn +4-7%, m191).
__global__ __launch_bounds__(256) void attn_kernel(
    const short* __restrict__ Q, const short* __restrict__ K,
    const short* __restrict__ Vt, short* __restrict__ O) {
  __shared__ short Ks[2 * 64 * 64];    // [buf][j][d], seg-swizzled (seg ^ row&7)
  __shared__ short Vs[2 * 64 * 64];    // [buf][d][j], seg-swizzled

  const int tid = threadIdx.x;
  const int wave = tid >> 6, lane = tid & 63;
  const int quad = lane >> 4, l15 = lane & 15;
  const int blk = blockIdx.x;          // 0..511
  const int xcd = blk & 7, slot = blk >> 3;   // slot 0..63
  const int bh = (slot >> 4) * 8 + xcd;       // 4 bh-groups per XCD
  const int qt = slot & 15;                   // 16 q-tiles per bh
  const int b = bh >> 3, h = bh & 7;
  const int i0 = qt * 128 + wave * 32;

  const int idx0 = tid, idx1 = 256 + tid;
  const int row0 = idx0 >> 3, sg0 = (idx0 & 7) ^ (row0 & 7);
  const int row1 = idx1 >> 3, sg1 = (idx1 & 7) ^ (row1 & 7);
  const short* Kb = K + (size_t)bh * 2048 * 64;
  const short* Vb = Vt + (size_t)bh * 64 * 2048;

  // Q as B-operand fragments: [it][ks]; i = it*16+l15, d = ks*32+quad*8+e
  bf16x8 qf[2][2];
#pragma unroll
  for (int it = 0; it < 2; ++it)
#pragma unroll
    for (int ks = 0; ks < 2; ++ks)
      qf[it][ks] = *(const bf16x8*)(Q + ((size_t)bh * 2048 + i0 + it * 16 + l15) * 64 + ks * 32 + quad * 8);

  bf16x8 ones;
#pragma unroll
  for (int c = 0; c < 8; ++c) ones[c] = (short)0x3F80;

  fx4 oacc[2][4];                      // [it][dt], O^T: row d=quad*4+r, col i=l15
  fx4 acc_l[2] = { fx4{0.f,0.f,0.f,0.f}, fx4{0.f,0.f,0.f,0.f} };
#pragma unroll
  for (int it = 0; it < 2; ++it)
#pragma unroll
    for (int dt = 0; dt < 4; ++dt) oacc[it][dt] = fx4{0.f, 0.f, 0.f, 0.f};

  // prologue: DMA tile 0 -> buf 0 (LDS dest linear: base + lane*16)
  gld16(Kb + (size_t)row0 * 64 + sg0 * 8, Ks + wave * 512);
  gld16(Kb + (size_t)row1 * 64 + sg1 * 8, Ks + 2048 + wave * 512);
  gld16(Vb + (size_t)row0 * 2048 + sg0 * 8, Vs + wave * 512);
  gld16(Vb + (size_t)row1 * 2048 + sg1 * 8, Vs + 2048 + wave * 512);

  for (int j0 = 0; j0 < 2048; j0 += 64) {
    const int cur = (j0 >> 6) & 1;
    bar_vm_lgkm();   // buf[cur] DMA complete; every wave's prior LDS reads drained
    if (j0 + 64 < 2048) {              // stage next tile into buf[cur^1]
      const int jn = j0 + 64;
      const int nb = (cur ^ 1) * 4096;
      gld16(Kb + (size_t)(jn + row0) * 64 + sg0 * 8, Ks + nb + wave * 512);
      gld16(Kb + (size_t)(jn + row1) * 64 + sg1 * 8, Ks + nb + 2048 + wave * 512);
      gld16(Vb + (size_t)row0 * 2048 + jn + sg0 * 8, Vs + nb + wave * 512);
      gld16(Vb + (size_t)row1 * 2048 + jn + sg1 * 8, Vs + nb + 2048 + wave * 512);
    }
    const short* Kc = Ks + cur * 4096;
    const short* Vc = Vs + cur * 4096;

    // ---- S^T = K · Q^T : each kf read feeds BOTH 16-row groups ----
    fx4 s[2][4];
#pragma unroll
    for (int it = 0; it < 2; ++it)
#pragma unroll
      for (int jt = 0; jt < 4; ++jt) s[it][jt] = fx4{0.f, 0.f, 0.f, 0.f};
    __builtin_amdgcn_s_setprio(1);
#pragma unroll
    for (int ks = 0; ks < 2; ++ks) {
#pragma unroll
      for (int jt = 0; jt < 4; ++jt) {
        bf16x8 kf = *(const bf16x8*)(Kc + (jt * 16 + l15) * 64 + (((ks * 4 + quad) ^ (l15 & 7)) * 8));
#pragma unroll
        for (int it = 0; it < 2; ++it)
          s[it][jt] = __builtin_amdgcn_mfma_f32_16x16x32_bf16(kf, qf[it][ks], s[it][jt], 0, 0, 0);
      }
    }
    __builtin_amdgcn_s_setprio(0);

    // ---- p = exp2(s); in-register quad-butterfly to PV B-operand layout ----
    bf16x8 pfr[2][2];                  // [it][kj]
#pragma unroll
    for (int it = 0; it < 2; ++it) {
      unsigned W[4][2];                // [jt][h]: bf16x2 of j = 16jt+4q+2h,+1
#pragma unroll
      for (int jt = 0; jt < 4; ++jt) {
#pragma unroll
        for (int r = 0; r < 4; ++r) s[it][jt][r] = EXP2(s[it][jt][r]);
        W[jt][0] = pk2(s[it][jt][0], s[it][jt][1]);
        W[jt][1] = pk2(s[it][jt][2], s[it][jt][3]);
      }
#pragma unroll
      for (int k = 0; k < 2; ++k) {    // k = kj = b5
        union { unsigned u[4]; bf16x8 v; } pw;
#pragma unroll
        for (int hh = 0; hh < 2; ++hh) {  // hh = b1
          uint32x2 a = __builtin_amdgcn_permlane32_swap(W[2 * k][hh], W[2 * k + 1][hh], false, false);
          uint32x2 t = __builtin_amdgcn_permlane16_swap(a[0], a[1], false, false);
          pw.u[hh] = t[0];             // b2=0 -> word m=hh
          pw.u[2 + hh] = t[1];         // b2=1 -> word m=2+hh
        }
        pfr[it][k] = pw.v;
      }
    }

    // ---- O^T += V^T · P^T ; l += 1 · P^T (all operands in registers) ----
    __builtin_amdgcn_s_setprio(1);
#pragma unroll
    for (int kj = 0; kj < 2; ++kj) {
#pragma unroll
      for (int it = 0; it < 2; ++it)
        acc_l[it] = __builtin_amdgcn_mfma_f32_16x16x32_bf16(ones, pfr[it][kj], acc_l[it], 0, 0, 0);
#pragma unroll
      for (int dt = 0; dt < 4; ++dt) {
        bf16x8 vf = *(const bf16x8*)(Vc + (dt * 16 + l15) * 64 + (((kj * 4 + quad) ^ (l15 & 7)) * 8));
#pragma unroll
        for (int it = 0; it < 2; ++it)
          oacc[it][dt] = __builtin_amdgcn_mfma_f32_16x16x32_bf16(vf, pfr[it][kj], oacc[it][dt], 0, 0, 0);
      }
    }
    __builtin_amdgcn_s_setprio(0);
  }

  // ---- normalize + write O bf16 [b][n=i][h*64+d]; 4 consecutive d -> b64 ----
#pragma unroll
  for (int it = 0; it < 2; ++it) {
    float inv = __builtin_amdgcn_rcpf(acc_l[it][0]);
    size_t rowbase = ((size_t)b * 2048 + i0 + it * 16 + l15) * 512 + h * 64;
#pragma unroll
    for (int dt = 0; dt < 4; ++dt) {
      fx4 o = oacc[it][dt] * inv;
      *(uint2*)(O + rowbase + dt * 16 + quad * 4) = pk4(o);
    }
  }
}

// ---------- launch ----------
extern "C" void kernel_launch(void* const* d_in, const int* in_sizes, int n_in,
                              void* d_out, int out_size, void* d_ws, size_t ws_size,
                              hipStream_t stream) {
  const float* x   = (const float*)d_in[0];
  const float* Wq  = (const float*)d_in[1];
  const float* Wkv = (const float*)d_in[2];
  const float* Wo  = (const float*)d_in[3];
  const float* bo  = (const float*)d_in[4];
  float* out = (float*)d_out;

  char* p = (char*)d_ws;
  short* xb    = (short*)p; p += (size_t)8192 * 512 * 2;   // x bf16 [8192,512]
  short* WallT = (short*)p; p += (size_t)1536 * 512 * 2;   // [Wq|Wkv]^T bf16 [1536,512]
  short* WoT   = (short*)p; p += (size_t)512 * 512 * 2;    // Wo^T bf16 [512,512]
  short* qb    = (short*)p; p += (size_t)32 * 2048 * 64 * 2;  // [bh,n,d]
  short* kb    = (short*)p; p += (size_t)32 * 2048 * 64 * 2;  // [bh,n,d]
  short* vTb   = (short*)p; p += (size_t)32 * 64 * 2048 * 2;  // [bh,d,n]
  short* Ob    = (short*)p; p += (size_t)8192 * 512 * 2;   // attn out bf16 [8192,512]

  const float qscale = 0.125f * 1.4426950408889634f;  // d^-0.5 * log2(e)

  prep_kernel<<<5120, 256, 0, stream>>>(x, Wq, Wkv, Wo, xb, WallT, WoT, qscale);
  gemm_qkv<<<768, 256, 0, stream>>>(xb, WallT, qb, kb, vTb);
  attn_kernel<<<512, 256, 0, stream>>>(qb, kb, vTb, Ob);
  gemm_out<<<dim3(4, 128), 256, 0, stream>>>(Ob, WoT, out, bo);
}

// Round 4
// 156.422 us; speedup vs baseline: 1.0771x; 1.0599x over previous
//
#include <hip/hip_runtime.h>
#include <hip/hip_bf16.h>

// ---------- types ----------
typedef short bf16x8 __attribute__((ext_vector_type(8)));   // 8 bf16 = 4 VGPR (MFMA A/B frag)
typedef float fx4    __attribute__((ext_vector_type(4)));   // MFMA C/D frag
typedef unsigned uint32x2 __attribute__((ext_vector_type(2)));

#if __has_builtin(__builtin_amdgcn_exp2f)
#define EXP2 __builtin_amdgcn_exp2f
#else
#define EXP2 exp2f
#endif

// packed fp32x2 -> bf16x2 (RNE), emits v_cvt_pk_bf16_f32 on gfx950
__device__ __forceinline__ unsigned pk2(float a, float b) {
  union { __hip_bfloat162 h; unsigned u; } cv;
  cv.h = __float22bfloat162_rn(float2{a, b});
  return cv.u;
}
__device__ __forceinline__ uint2 pk4(const fx4& v) {
  uint2 r;
  r.x = pk2(v[0], v[1]);
  r.y = pk2(v[2], v[3]);
  return r;
}

// async global->LDS, 16B per lane. LDS dest = wave-uniform base + lane*16.
__device__ __forceinline__ void gld16(const void* g, void* l) {
  __builtin_amdgcn_global_load_lds(
      (const __attribute__((address_space(1))) unsigned int*)g,
      (__attribute__((address_space(3))) unsigned int*)l, 16, 0, 0);
}

// ---- barriers that do NOT drain vmcnt (keep register prefetches in flight) ----
__device__ __forceinline__ void bar_raw() {
  asm volatile("s_barrier" ::: "memory");
}
__device__ __forceinline__ void bar_lgkm() {
  asm volatile("s_waitcnt lgkmcnt(0)\ns_barrier" ::: "memory");
}
__device__ __forceinline__ void bar_lgkm_vm4() {
  asm volatile("s_waitcnt vmcnt(4) lgkmcnt(0)\ns_barrier" ::: "memory");
}
// full drain barrier (for gld16 double-buffer handoff in attn)
__device__ __forceinline__ void bar_vm_lgkm() {
  asm volatile("s_waitcnt vmcnt(0) lgkmcnt(0)\ns_barrier" ::: "memory");
}
__device__ __forceinline__ void cfence() { asm volatile("" ::: "memory"); }

// ---------- prep: x cast + both weight transposes, one launch ----------
__global__ __launch_bounds__(256) void prep_kernel(
    const float* __restrict__ x, const float* __restrict__ Wq,
    const float* __restrict__ Wkv, const float* __restrict__ Wo,
    short* __restrict__ xb, short* __restrict__ WallT, short* __restrict__ WoT,
    float qscale) {
  const int bx = blockIdx.x, tid = threadIdx.x;
  if (bx < 4096) {
    int i = bx * 256 + tid;
    const float4 s = *(const float4*)(x + (size_t)i * 4);
    uint2 o; o.x = pk2(s.x, s.y); o.y = pk2(s.z, s.w);
    *(uint2*)(xb + (size_t)i * 4) = o;
    return;
  }
  __shared__ float t[32][33];
  const int idx = bx - 4096;            // 0..1023
  const int wb = idx & 63, kt = (idx >> 6) * 32;
  const bool mode0 = wb < 48;
  const int ct = (mode0 ? wb : wb - 48) * 32;
  const int tx = tid & 31, ty = tid >> 5;
  short* outT = mode0 ? WallT : WoT;
#pragma unroll
  for (int s = 0; s < 4; ++s) {
    int k = kt + ty + s * 8;
    int c = ct + tx;
    float v;
    if (mode0) v = (c < 512) ? Wq[(size_t)k * 512 + c] * qscale
                             : Wkv[(size_t)k * 1024 + (c - 512)];
    else       v = Wo[(size_t)k * 512 + c];
    t[ty + s * 8][tx] = v;
  }
  __syncthreads();
#pragma unroll
  for (int s = 0; s < 4; ++s) {
    int c = ct + ty + s * 8;
    int k = kt + tx;
    unsigned u = __float_as_uint(t[tx][ty + s * 8]);
    u = (u + 0x7fffu + ((u >> 16) & 1u)) >> 16;
    outT[(size_t)c * 512 + k] = (short)u;
  }
}

// ---------- QKV GEMM: 128x128 tile, BK=64, A reg-prefetch + B gld16/vmcnt(4) ----------
// XCD-residency swizzle: 768 blocks flat; xcd = blk&7 (HW round-robin), each
// XCD gets 8 m-panels (1MB A) + the whole 1.5MB B panel -> <4MB L2, L2-resident.
__global__ __launch_bounds__(256) void gemm_qkv(
    const short* __restrict__ A, const short* __restrict__ Bt,
    short* __restrict__ oq, short* __restrict__ ok, short* __restrict__ ovT) {
  __shared__ short As[2 * 128 * 32];   // [slab][row][32k]
  __shared__ short Bs[2 * 128 * 32];
  const int K = 512;
  const int tid = threadIdx.x;
  const int wave = tid >> 6, lane = tid & 63;
  const int quad = lane >> 4, l15 = lane & 15;
  const int wm = wave >> 1, wn = wave & 1;
  const int blk = blockIdx.x;          // 0..767
  const int xcd = blk & 7, slot = blk >> 3;      // slot 0..95
  const int m0 = ((slot / 12) * 8 + xcd) * 128;  // m-tile 0..63
  const int n0 = (slot % 12) * 128;              // n-tile 0..11
  const bool swapped = (n0 < 1024);

  int arow[4], aoff[4];
#pragma unroll
  for (int c = 0; c < 4; ++c) {
    int u = c * 256 + tid;
    int slab = u >> 9, r2 = u & 511;
    arow[c] = r2 >> 2;
    aoff[c] = slab * 32 + (r2 & 3) * 8;
  }

  fx4 acc[4][4];
#pragma unroll
  for (int i = 0; i < 4; ++i)
#pragma unroll
    for (int j = 0; j < 4; ++j) acc[i][j] = fx4{0.f, 0.f, 0.f, 0.f};

  bf16x8 apre[4];
#pragma unroll
  for (int c = 0; c < 4; ++c)
    apre[c] = *(const bf16x8*)(A + (size_t)(m0 + arow[c]) * K + aoff[c]);

  for (int k0 = 0; k0 < K; k0 += 64) {
    bar_raw();
#pragma unroll
    for (int c = 0; c < 4; ++c)
      *(bf16x8*)(As + (size_t)(c * 256 + tid) * 8) = apre[c];
#pragma unroll
    for (int c = 0; c < 4; ++c) {
      int u = c * 256 + tid;
      int slab = u >> 9, r2 = u & 511;
      gld16(Bt + (size_t)(n0 + (r2 >> 2)) * K + k0 + slab * 32 + (r2 & 3) * 8,
            Bs + (size_t)(c * 256 + wave * 64) * 8);
    }
    cfence();
    {
      int kn = (k0 + 64) & 511;
#pragma unroll
      for (int c = 0; c < 4; ++c)
        apre[c] = *(const bf16x8*)(A + (size_t)(m0 + arow[c]) * K + kn + aoff[c]);
    }
    bar_lgkm_vm4();

#pragma unroll
    for (int ks2 = 0; ks2 < 2; ++ks2) {
      bf16x8 af[4], bfr[4];
#pragma unroll
      for (int i = 0; i < 4; ++i)
        af[i] = *(const bf16x8*)(As + ks2 * 4096 + (wm * 64 + i * 16 + l15) * 32 + quad * 8);
#pragma unroll
      for (int i = 0; i < 4; ++i)
        bfr[i] = *(const bf16x8*)(Bs + ks2 * 4096 + (wn * 64 + i * 16 + l15) * 32 + quad * 8);
      if (swapped) {
#pragma unroll
        for (int mi = 0; mi < 4; ++mi)
#pragma unroll
          for (int ni = 0; ni < 4; ++ni)
            acc[mi][ni] = __builtin_amdgcn_mfma_f32_16x16x32_bf16(bfr[ni], af[mi], acc[mi][ni], 0, 0, 0);
      } else {
#pragma unroll
        for (int mi = 0; mi < 4; ++mi)
#pragma unroll
          for (int ni = 0; ni < 4; ++ni)
            acc[mi][ni] = __builtin_amdgcn_mfma_f32_16x16x32_bf16(af[mi], bfr[ni], acc[mi][ni], 0, 0, 0);
      }
    }
  }

  const int rowb = m0 + wm * 64;
  const int colb = n0 + wn * 64;
  const int cls = n0 >> 9;  // 0=q, 1=k, 2=v
  if (cls < 2) {
    short* base = (cls == 0) ? oq : ok;
#pragma unroll
    for (int mi = 0; mi < 4; ++mi) {
      int t = rowb + mi * 16 + l15;
      int bb = t >> 11, ii = t & 2047;
#pragma unroll
      for (int ni = 0; ni < 4; ++ni) {
        int f = (colb + ni * 16 + quad * 4) & 511;
        int hh = f >> 6, dd = f & 63;
        *(uint2*)(base + ((size_t)(bb * 8 + hh) * 2048 + ii) * 64 + dd) = pk4(acc[mi][ni]);
      }
    }
  } else {
#pragma unroll
    for (int mi = 0; mi < 4; ++mi) {
      int rbase = rowb + mi * 16 + quad * 4;
      int bb = rbase >> 11;
      int ii = rbase & 2047;
#pragma unroll
      for (int ni = 0; ni < 4; ++ni) {
        int c = (colb + ni * 16 + l15) & 511;
        int hh = c >> 6, dd = c & 63;
        *(uint2*)(ovT + ((size_t)(bb * 8 + hh) * 64 + dd) * 2048 + ii) = pk4(acc[mi][ni]);
      }
    }
  }
}

// ---------- out-proj GEMM: 64x128 tile, BK=64, full reg-prefetch, fp32+bias ----------
__global__ __launch_bounds__(256) void gemm_out(
    const short* __restrict__ A, const short* __restrict__ Bt,
    float* __restrict__ of, const float* __restrict__ bias) {
  __shared__ short As[2 * 64 * 32];    // 8KB
  __shared__ short Bs[2 * 128 * 32];   // 16KB
  const int K = 512, N = 512;
  const int tid = threadIdx.x;
  const int wave = tid >> 6, lane = tid & 63;
  const int quad = lane >> 4, l15 = lane & 15;
  const int wm = wave >> 1, wn = wave & 1;
  const int m0 = blockIdx.y * 64, n0 = blockIdx.x * 128;

  int arow[2], aoff[2], brow[4], boff[4];
#pragma unroll
  for (int c = 0; c < 2; ++c) {
    int u = c * 256 + tid;
    int slab = u >> 8, r2 = u & 255;
    arow[c] = r2 >> 2; aoff[c] = slab * 32 + (r2 & 3) * 8;
  }
#pragma unroll
  for (int c = 0; c < 4; ++c) {
    int u = c * 256 + tid;
    int slab = u >> 9, r2 = u & 511;
    brow[c] = r2 >> 2; boff[c] = slab * 32 + (r2 & 3) * 8;
  }

  fx4 acc[2][4];
#pragma unroll
  for (int i = 0; i < 2; ++i)
#pragma unroll
    for (int j = 0; j < 4; ++j) acc[i][j] = fx4{0.f, 0.f, 0.f, 0.f};

  bf16x8 apre[2], bpre[4];
#pragma unroll
  for (int c = 0; c < 2; ++c)
    apre[c] = *(const bf16x8*)(A + (size_t)(m0 + arow[c]) * K + aoff[c]);
#pragma unroll
  for (int c = 0; c < 4; ++c)
    bpre[c] = *(const bf16x8*)(Bt + (size_t)(n0 + brow[c]) * K + boff[c]);

  for (int k0 = 0; k0 < K; k0 += 64) {
    bar_raw();
#pragma unroll
    for (int c = 0; c < 2; ++c)
      *(bf16x8*)(As + (size_t)(c * 256 + tid) * 8) = apre[c];
#pragma unroll
    for (int c = 0; c < 4; ++c)
      *(bf16x8*)(Bs + (size_t)(c * 256 + tid) * 8) = bpre[c];
    {
      int kn = (k0 + 64) & 511;
#pragma unroll
      for (int c = 0; c < 2; ++c)
        apre[c] = *(const bf16x8*)(A + (size_t)(m0 + arow[c]) * K + kn + aoff[c]);
#pragma unroll
      for (int c = 0; c < 4; ++c)
        bpre[c] = *(const bf16x8*)(Bt + (size_t)(n0 + brow[c]) * K + kn + boff[c]);
    }
    bar_lgkm();

#pragma unroll
    for (int ks2 = 0; ks2 < 2; ++ks2) {
      bf16x8 af[2], bfr[4];
#pragma unroll
      for (int i = 0; i < 2; ++i)
        af[i] = *(const bf16x8*)(As + ks2 * 2048 + (wm * 32 + i * 16 + l15) * 32 + quad * 8);
#pragma unroll
      for (int i = 0; i < 4; ++i)
        bfr[i] = *(const bf16x8*)(Bs + ks2 * 4096 + (wn * 64 + i * 16 + l15) * 32 + quad * 8);
#pragma unroll
      for (int mi = 0; mi < 2; ++mi)
#pragma unroll
        for (int ni = 0; ni < 4; ++ni)
          acc[mi][ni] = __builtin_amdgcn_mfma_f32_16x16x32_bf16(af[mi], bfr[ni], acc[mi][ni], 0, 0, 0);
    }
  }

  const int rowb = m0 + wm * 32;
  const int colb = n0 + wn * 64;
#pragma unroll
  for (int mi = 0; mi < 2; ++mi)
#pragma unroll
    for (int ni = 0; ni < 4; ++ni) {
      int cg = colb + ni * 16 + l15;
      float bv = bias[cg];
#pragma unroll
      for (int r = 0; r < 4; ++r) {
        int rg = rowb + mi * 16 + quad * 4 + r;
        of[(size_t)rg * N + cg] = acc[mi][ni][r] + bv;
      }
    }
}

// ---------- flash attention v5: cross-tile software pipeline (att[2]/T15) ----------
// Q,K: [bh=32][2048][64] bf16 ; Vt: [bh][64][2048] bf16 ; O: [b][2048][512] bf16
// v2/v3/v4 nulls bounded the problem: not LDS-throughput, not conflicts, not
// occupancy, not fetch locality. MfmaUtil 24% + VALUBusy 44%, nothing
// saturated => m233-style 2-phase serialization: within each iteration the
// wave runs QK -> exp2/butterfly -> PV as a SERIAL chain; MFMA idles during
// softmax, VALU idles during MFMA.
// v5 breaks the chain across j-tiles: iteration t runs QK^T(t) [MFMA, from
// LDS] concurrently with softmax(t-1) [VALU, regs] and PV(t-1) [MFMA, regs
// only: pfr x vf]. V fragments are REGISTER-carried (vf, 32 VGPR) because
// DMA(t+1) overwrites the LDS buffer that held V(t-1) mid-phase. Unroll-2
// with named A/B register sets (no runtime indexing -> no scratch).
// Same 2-buffer LDS, one full-drain barrier per tile, DMA issued right after
// the barrier gets the whole phase to land (L2-resident via XCD swizzle).
// VGPR ~220 (launch_bounds(256,2)); grid caps CU at 2 blocks anyway.
__global__ __launch_bounds__(256, 2) void attn_kernel(
    const short* __restrict__ Q, const short* __restrict__ K,
    const short* __restrict__ Vt, short* __restrict__ O) {
  __shared__ short Ks[2 * 64 * 64];    // [buf][j][d], seg-swizzled (seg ^ row&7)
  __shared__ short Vs[2 * 64 * 64];    // [buf][d][j], seg-swizzled

  const int tid = threadIdx.x;
  const int wave = tid >> 6, lane = tid & 63;
  const int quad = lane >> 4, l15 = lane & 15;
  const int blk = blockIdx.x;          // 0..511
  const int xcd = blk & 7, slot = blk >> 3;   // slot 0..63
  const int bh = (slot >> 4) * 8 + xcd;       // 4 bh-groups per XCD (L2-resident K/V)
  const int qt = slot & 15;                   // 16 q-tiles per bh
  const int b = bh >> 3, h = bh & 7;
  const int i0 = qt * 128 + wave * 32;

  const int idx0 = tid, idx1 = 256 + tid;
  const int row0 = idx0 >> 3, sg0 = (idx0 & 7) ^ (row0 & 7);
  const int row1 = idx1 >> 3, sg1 = (idx1 & 7) ^ (row1 & 7);
  const short* Kb = K + (size_t)bh * 2048 * 64;
  const short* Vb = Vt + (size_t)bh * 64 * 2048;

  // Q as B-operand fragments: [it][ks]; i = it*16+l15, d = ks*32+quad*8+e
  bf16x8 qf[2][2];
#pragma unroll
  for (int it = 0; it < 2; ++it)
#pragma unroll
    for (int ks = 0; ks < 2; ++ks)
      qf[it][ks] = *(const bf16x8*)(Q + ((size_t)bh * 2048 + i0 + it * 16 + l15) * 64 + ks * 32 + quad * 8);

  bf16x8 ones;
#pragma unroll
  for (int c = 0; c < 8; ++c) ones[c] = (short)0x3F80;

  fx4 oacc[2][4];                      // [it][dt], O^T: row d=quad*4+r, col i=l15
  fx4 acc_l[2] = { fx4{0.f,0.f,0.f,0.f}, fx4{0.f,0.f,0.f,0.f} };
#pragma unroll
  for (int it = 0; it < 2; ++it)
#pragma unroll
    for (int dt = 0; dt < 4; ++dt) oacc[it][dt] = fx4{0.f, 0.f, 0.f, 0.f};

  // DMA one j-tile (K 8KB + V 8KB) into buffer bufsel; LDS dest linear,
  // global src pre-swizzled (seg ^ row&7) so LDS layout lands swizzled.
  auto DMA = [&](int jn, int bufsel) {
    const int nb = bufsel * 4096;
    gld16(Kb + (size_t)(jn + row0) * 64 + sg0 * 8, Ks + nb + wave * 512);
    gld16(Kb + (size_t)(jn + row1) * 64 + sg1 * 8, Ks + nb + 2048 + wave * 512);
    gld16(Vb + (size_t)row0 * 2048 + jn + sg0 * 8, Vs + nb + wave * 512);
    gld16(Vb + (size_t)row1 * 2048 + jn + sg1 * 8, Vs + nb + 2048 + wave * 512);
  };

  // S^T(t) = K·Q^T from LDS buffer into named reg tile s[2][4]
  auto QK = [&](const short* Kc, fx4 (&s)[2][4]) {
#pragma unroll
    for (int it = 0; it < 2; ++it)
#pragma unroll
      for (int jt = 0; jt < 4; ++jt) s[it][jt] = fx4{0.f, 0.f, 0.f, 0.f};
#pragma unroll
    for (int ks = 0; ks < 2; ++ks) {
#pragma unroll
      for (int jt = 0; jt < 4; ++jt) {
        bf16x8 kf = *(const bf16x8*)(Kc + (jt * 16 + l15) * 64 + (((ks * 4 + quad) ^ (l15 & 7)) * 8));
#pragma unroll
        for (int it = 0; it < 2; ++it)
          s[it][jt] = __builtin_amdgcn_mfma_f32_16x16x32_bf16(kf, qf[it][ks], s[it][jt], 0, 0, 0);
      }
    }
  };

  // V fragments tile t -> registers (so PV(t) can run while DMA(t+2) owns LDS)
  auto VLOAD = [&](const short* Vc, bf16x8 (&vf)[2][4]) {
#pragma unroll
    for (int kj = 0; kj < 2; ++kj)
#pragma unroll
      for (int dt = 0; dt < 4; ++dt)
        vf[kj][dt] = *(const bf16x8*)(Vc + (dt * 16 + l15) * 64 + (((kj * 4 + quad) ^ (l15 & 7)) * 8));
  };

  // softmax + butterfly + PV of a PREVIOUS tile, all register operands
  auto SMPV = [&](fx4 (&s)[2][4], bf16x8 (&vf)[2][4]) {
#pragma unroll
    for (int it = 0; it < 2; ++it) {
      unsigned W[4][2];                // [jt][h]: bf16x2 of j = 16jt+4q+2h,+1
#pragma unroll
      for (int jt = 0; jt < 4; ++jt) {
#pragma unroll
        for (int r = 0; r < 4; ++r) s[it][jt][r] = EXP2(s[it][jt][r]);
        W[jt][0] = pk2(s[it][jt][0], s[it][jt][1]);
        W[jt][1] = pk2(s[it][jt][2], s[it][jt][3]);
      }
#pragma unroll
      for (int k = 0; k < 2; ++k) {    // k = kj = b5
        union { unsigned u[4]; bf16x8 v; } pw;
#pragma unroll
        for (int hh = 0; hh < 2; ++hh) {  // hh = b1
          uint32x2 a = __builtin_amdgcn_permlane32_swap(W[2 * k][hh], W[2 * k + 1][hh], false, false);
          uint32x2 t = __builtin_amdgcn_permlane16_swap(a[0], a[1], false, false);
          pw.u[hh] = t[0];             // b2=0 -> word m=hh
          pw.u[2 + hh] = t[1];         // b2=1 -> word m=2+hh
        }
        acc_l[it] = __builtin_amdgcn_mfma_f32_16x16x32_bf16(ones, pw.v, acc_l[it], 0, 0, 0);
#pragma unroll
        for (int dt = 0; dt < 4; ++dt)
          oacc[it][dt] = __builtin_amdgcn_mfma_f32_16x16x32_bf16(vf[k][dt], pw.v, oacc[it][dt], 0, 0, 0);
      }
    }
  };

  fx4 sA[2][4], sB[2][4];
  bf16x8 vfA[2][4], vfB[2][4];

  // prologue: tile0 -> buf0; start tile1 -> buf1; QK(0)
  DMA(0, 0);
  bar_vm_lgkm();                       // tile0 resident
  DMA(64, 1);
  QK(Ks, sA);
  VLOAD(Vs, vfA);

  // steady state: 15 iterations handle tiles 1..30 (QK) / 0..29 (SMPV)
  for (int t1 = 1; t1 <= 29; t1 += 2) {
    bar_vm_lgkm();                     // tile t1 (buf1) resident; buf0 reads drained
    DMA((t1 + 1) << 6, 0);             // tile t1+1 -> buf0
    QK(Ks + 4096, sB);                 // MFMA stream: QK(t1)
    VLOAD(Vs + 4096, vfB);
    SMPV(sA, vfA);                     // VALU+MFMA stream: finish tile t1-1
    bar_vm_lgkm();                     // tile t1+1 (buf0) resident; buf1 reads drained
    DMA((t1 + 2) << 6, 1);             // tile t1+2 -> buf1 (t1=29 -> tile31)
    QK(Ks, sA);                        // QK(t1+1)
    VLOAD(Vs, vfA);
    SMPV(sB, vfB);                     // finish tile t1
  }

  // tail: tile31
  bar_vm_lgkm();                       // tile31 (buf1) resident
  QK(Ks + 4096, sB);
  VLOAD(Vs + 4096, vfB);
  SMPV(sA, vfA);                       // finish tile 30
  SMPV(sB, vfB);                       // finish tile 31

  // ---- normalize + write O bf16 [b][n=i][h*64+d]; 4 consecutive d -> b64 ----
#pragma unroll
  for (int it = 0; it < 2; ++it) {
    float inv = __builtin_amdgcn_rcpf(acc_l[it][0]);
    size_t rowbase = ((size_t)b * 2048 + i0 + it * 16 + l15) * 512 + h * 64;
#pragma unroll
    for (int dt = 0; dt < 4; ++dt) {
      fx4 o = oacc[it][dt] * inv;
      *(uint2*)(O + rowbase + dt * 16 + quad * 4) = pk4(o);
    }
  }
}

// ---------- launch ----------
extern "C" void kernel_launch(void* const* d_in, const int* in_sizes, int n_in,
                              void* d_out, int out_size, void* d_ws, size_t ws_size,
                              hipStream_t stream) {
  const float* x   = (const float*)d_in[0];
  const float* Wq  = (const float*)d_in[1];
  const float* Wkv = (const float*)d_in[2];
  const float* Wo  = (const float*)d_in[3];
  const float* bo  = (const float*)d_in[4];
  float* out = (float*)d_out;

  char* p = (char*)d_ws;
  short* xb    = (short*)p; p += (size_t)8192 * 512 * 2;   // x bf16 [8192,512]
  short* WallT = (short*)p; p += (size_t)1536 * 512 * 2;   // [Wq|Wkv]^T bf16 [1536,512]
  short* WoT   = (short*)p; p += (size_t)512 * 512 * 2;    // Wo^T bf16 [512,512]
  short* qb    = (short*)p; p += (size_t)32 * 2048 * 64 * 2;  // [bh,n,d]
  short* kb    = (short*)p; p += (size_t)32 * 2048 * 64 * 2;  // [bh,n,d]
  short* vTb   = (short*)p; p += (size_t)32 * 64 * 2048 * 2;  // [bh,d,n]
  short* Ob    = (short*)p; p += (size_t)8192 * 512 * 2;   // attn out bf16 [8192,512]

  const float qscale = 0.125f * 1.4426950408889634f;  // d^-0.5 * log2(e)

  prep_kernel<<<5120, 256, 0, stream>>>(x, Wq, Wkv, Wo, xb, WallT, WoT, qscale);
  gemm_qkv<<<768, 256, 0, stream>>>(xb, WallT, qb, kb, vTb);
  attn_kernel<<<512, 256, 0, stream>>>(qb, kb, vTb, Ob);
  gemm_out<<<dim3(4, 128), 256, 0, stream>>>(Ob, WoT, out, bo);
}